// Round 1
// baseline (2427.477 us; speedup 1.0000x reference)
//
#include <hip/hip_runtime.h>
#include <math.h>

#define N_PIX 16384
#define EMB 128
#define LN_EPS 1e-5f
#define INV_TEMP 10.0f

#define BQ 64
#define BK 64
#define KPAD 132   // padded row stride (dwords) for Q/K tiles: odd*4 -> conflict-free, 16B aligned
#define VSP 20     // padded row stride for V tile (16 cols), 80B rows keep float4 alignment

// ---------------------------------------------------------------------------
// Kernel 1: descriptor + MLP(6->128) + LayerNorm + MLP(128->128), one row/block
// ---------------------------------------------------------------------------
__global__ __launch_bounds__(128) void encode_kernel(
    const float* __restrict__ ego_cls, const float* __restrict__ ego_reg,
    const float* __restrict__ other_cls, const float* __restrict__ other_reg,
    const float* __restrict__ w1, const float* __restrict__ b1,
    const float* __restrict__ ln_g, const float* __restrict__ ln_b,
    const float* __restrict__ w2, const float* __restrict__ b2,
    float* __restrict__ ego_desc, float* __restrict__ other_desc)
{
    int r = blockIdx.x;
    const float* cls; const float* reg; float* outp; int p;
    if (r < N_PIX) { cls = ego_cls;   reg = ego_reg;   outp = ego_desc;   p = r; }
    else           { cls = other_cls; reg = other_reg; outp = other_desc; p = r - N_PIX; }

    int j = threadIdx.x;

    // 6-dim descriptor (recomputed per thread; trivially cheap)
    float x0 = reg[3*N_PIX + p];
    float x1 = reg[4*N_PIX + p];
    float x2 = reg[5*N_PIX + p];
    float th = reg[6*N_PIX + p];
    float x3 = sinf(th);
    float x4 = cosf(th);
    float x5 = fmaxf(cls[p], cls[N_PIX + p]);

    float h = x0*w1[0*EMB+j] + x1*w1[1*EMB+j] + x2*w1[2*EMB+j]
            + x3*w1[3*EMB+j] + x4*w1[4*EMB+j] + x5*w1[5*EMB+j] + b1[j];
    h = fmaxf(h, 0.f);

    __shared__ float hn[EMB];
    __shared__ float red[4];

    // mean/var over 128 (2 waves): wave shuffle reduce then LDS combine
    float s = h, s2 = h*h;
    #pragma unroll
    for (int off = 32; off >= 1; off >>= 1) {
        s  += __shfl_xor(s,  off);
        s2 += __shfl_xor(s2, off);
    }
    int wid = j >> 6;
    if ((j & 63) == 0) { red[wid] = s; red[2+wid] = s2; }
    __syncthreads();
    float tot  = red[0] + red[1];
    float tot2 = red[2] + red[3];
    float mu  = tot * (1.f/EMB);
    float var = tot2 * (1.f/EMB) - mu*mu;          // biased var (matches jnp.var)
    float rstd = rsqrtf(var + LN_EPS);
    float hnj = (h - mu) * rstd * ln_g[j] + ln_b[j];
    hn[j] = hnj;
    __syncthreads();

    float acc = b2[j];
    #pragma unroll 8
    for (int k = 0; k < EMB; ++k)
        acc += hn[k] * w2[k*EMB + j];              // hn broadcast, w2 coalesced (L2-resident)
    outp[(size_t)p * EMB + j] = acc;
}

// ---------------------------------------------------------------------------
// Kernel 2: flash attention, f32.  grid = 256 blocks (64 queries each),
// block = 256 threads. Thread (tq,tk): queries {tq+16m}, keys {tk+16n}.
// PV accumulator acc[4 q][16 cols] lives in registers; 16-lane butterfly at end.
// ---------------------------------------------------------------------------
__device__ __forceinline__ void load_kv(
    const float* __restrict__ K, const float* __restrict__ ocls,
    const float* __restrict__ oreg, int kb0, int tid,
    float4 (&kreg)[8], float (&vreg)[4])
{
    #pragma unroll
    for (int r = 0; r < 8; ++r) {
        int idx = r*256 + tid;
        int k = idx >> 5, dk = (idx & 31) * 4;
        kreg[r] = *(const float4*)&K[(size_t)(kb0 + k)*EMB + dk];
    }
    #pragma unroll
    for (int r = 0; r < 4; ++r) {
        int idx = r*256 + tid;
        int c = idx >> 6, k = idx & 63;
        const float* vp = (c < 2) ? (ocls + c*N_PIX) : (oreg + (c-2)*N_PIX);
        vreg[r] = vp[kb0 + k];
    }
}

__global__ __launch_bounds__(256) void attn_kernel(
    const float* __restrict__ Q,     // ego_desc   [N][128]
    const float* __restrict__ K,     // other_desc [N][128]
    const float* __restrict__ other_cls, const float* __restrict__ other_reg,
    float* __restrict__ out)         // [16][N] (cls 0..1, reg 0..13 — concat order)
{
    extern __shared__ float smem[];
    float* Qs = smem;                  // BQ x KPAD
    float* Ks = Qs + BQ*KPAD;          // BK x KPAD
    float* Vs = Ks + BK*KPAD;          // BK x VSP

    const int tid = threadIdx.x;
    const int tq = tid >> 4, tk = tid & 15;
    const int q0 = blockIdx.x * BQ;

    // stage Q tile (once)
    #pragma unroll
    for (int r = 0; r < 8; ++r) {
        int idx = r*256 + tid;
        int q = idx >> 5, dq = (idx & 31) * 4;
        float4 v = *(const float4*)&Q[(size_t)(q0 + q)*EMB + dq];
        *(float4*)&Qs[q*KPAD + dq] = v;
    }

    float4 kreg[8]; float vreg[4];
    load_kv(K, other_cls, other_reg, 0, tid, kreg, vreg);

    float mrow[4], lrow[4], accv[4][16];
    #pragma unroll
    for (int m = 0; m < 4; ++m) {
        mrow[m] = -INFINITY; lrow[m] = 0.f;
        #pragma unroll
        for (int c = 0; c < 16; ++c) accv[m][c] = 0.f;
    }

    const int NT = N_PIX / BK;
    for (int t = 0; t < NT; ++t) {
        __syncthreads();   // prev-tile consumers done (also covers Q staging at t=0)
        #pragma unroll
        for (int r = 0; r < 8; ++r) {
            int idx = r*256 + tid;
            int k = idx >> 5, dk = (idx & 31) * 4;
            *(float4*)&Ks[k*KPAD + dk] = kreg[r];
        }
        #pragma unroll
        for (int r = 0; r < 4; ++r) {
            int idx = r*256 + tid;
            int c = idx >> 6, k = idx & 63;
            Vs[k*VSP + c] = vreg[r];
        }
        if (t + 1 < NT)   // prefetch next tile; latency hides under compute below
            load_kv(K, other_cls, other_reg, (t+1)*BK, tid, kreg, vreg);
        __syncthreads();   // K/V tile ready

        // ---- S = 10 * Q K^T  (4x4 per thread) ----
        float S[4][4];
        #pragma unroll
        for (int m = 0; m < 4; ++m)
            #pragma unroll
            for (int n = 0; n < 4; ++n) S[m][n] = 0.f;

        #pragma unroll 2
        for (int dd = 0; dd < 32; ++dd) {
            const int d0 = dd*4;
            float4 qa[4], kb[4];
            #pragma unroll
            for (int m = 0; m < 4; ++m) qa[m] = *(const float4*)&Qs[(tq+16*m)*KPAD + d0];
            #pragma unroll
            for (int n = 0; n < 4; ++n) kb[n] = *(const float4*)&Ks[(tk+16*n)*KPAD + d0];
            #pragma unroll
            for (int m = 0; m < 4; ++m)
                #pragma unroll
                for (int n = 0; n < 4; ++n)
                    S[m][n] += qa[m].x*kb[n].x + qa[m].y*kb[n].y
                             + qa[m].z*kb[n].z + qa[m].w*kb[n].w;
        }

        // ---- online softmax (row = 16-lane group over tk) ----
        #pragma unroll
        for (int m = 0; m < 4; ++m) {
            float mt = fmaxf(fmaxf(S[m][0]*INV_TEMP, S[m][1]*INV_TEMP),
                             fmaxf(S[m][2]*INV_TEMP, S[m][3]*INV_TEMP));
            mt = fmaxf(mt, __shfl_xor(mt, 1));
            mt = fmaxf(mt, __shfl_xor(mt, 2));
            mt = fmaxf(mt, __shfl_xor(mt, 4));
            mt = fmaxf(mt, __shfl_xor(mt, 8));
            float mn = fmaxf(mrow[m], mt);
            float sc = __expf(mrow[m] - mn);       // first tile: exp(-inf)=0
            mrow[m] = mn;
            float rsum = 0.f;
            #pragma unroll
            for (int n = 0; n < 4; ++n) {
                S[m][n] = __expf(S[m][n]*INV_TEMP - mn);
                rsum += S[m][n];
            }
            rsum += __shfl_xor(rsum, 1);
            rsum += __shfl_xor(rsum, 2);
            rsum += __shfl_xor(rsum, 4);
            rsum += __shfl_xor(rsum, 8);
            lrow[m] = lrow[m]*sc + rsum;
            #pragma unroll
            for (int c = 0; c < 16; ++c) accv[m][c] *= sc;
        }

        // ---- PV: acc[m][c] += p[m][n] * V[k_n][c] ----
        #pragma unroll
        for (int n = 0; n < 4; ++n) {
            const float* vr = &Vs[(tk+16*n)*VSP];
            float4 v0 = *(const float4*)&vr[0];
            float4 v1 = *(const float4*)&vr[4];
            float4 v2 = *(const float4*)&vr[8];
            float4 v3 = *(const float4*)&vr[12];
            #pragma unroll
            for (int m = 0; m < 4; ++m) {
                float pp = S[m][n];
                accv[m][0]  += pp*v0.x; accv[m][1]  += pp*v0.y;
                accv[m][2]  += pp*v0.z; accv[m][3]  += pp*v0.w;
                accv[m][4]  += pp*v1.x; accv[m][5]  += pp*v1.y;
                accv[m][6]  += pp*v1.z; accv[m][7]  += pp*v1.w;
                accv[m][8]  += pp*v2.x; accv[m][9]  += pp*v2.y;
                accv[m][10] += pp*v2.z; accv[m][11] += pp*v2.w;
                accv[m][12] += pp*v3.x; accv[m][13] += pp*v3.y;
                accv[m][14] += pp*v3.z; accv[m][15] += pp*v3.w;
            }
        }
    }

    // ---- reduce partial PV sums across the 16 tk-lanes, write out ----
    #pragma unroll
    for (int m = 0; m < 4; ++m) {
        #pragma unroll
        for (int c = 0; c < 16; ++c) {
            float v = accv[m][c];
            v += __shfl_xor(v, 1);
            v += __shfl_xor(v, 2);
            v += __shfl_xor(v, 4);
            v += __shfl_xor(v, 8);
            accv[m][c] = v;
        }
    }
    #pragma unroll
    for (int m = 0; m < 4; ++m) {
        float res = 0.f;
        #pragma unroll
        for (int c = 0; c < 16; ++c) if (tk == c) res = accv[m][c];  // static idx select
        out[(size_t)tk*N_PIX + (q0 + tq + 16*m)] = res / lrow[m];
    }
}

// ---------------------------------------------------------------------------
extern "C" void kernel_launch(void* const* d_in, const int* in_sizes, int n_in,
                              void* d_out, int out_size, void* d_ws, size_t ws_size,
                              hipStream_t stream) {
    const float* ego_cls   = (const float*)d_in[0];
    const float* ego_reg   = (const float*)d_in[1];
    const float* other_cls = (const float*)d_in[2];
    const float* other_reg = (const float*)d_in[3];
    const float* w1   = (const float*)d_in[4];
    const float* b1   = (const float*)d_in[5];
    const float* ln_g = (const float*)d_in[6];
    const float* ln_b = (const float*)d_in[7];
    const float* w2   = (const float*)d_in[8];
    const float* b2   = (const float*)d_in[9];

    float* ego_desc   = (float*)d_ws;                      // 16384*128 f32 = 8 MB
    float* other_desc = ego_desc + (size_t)N_PIX*EMB;      // 8 MB

    encode_kernel<<<2*N_PIX, 128, 0, stream>>>(
        ego_cls, ego_reg, other_cls, other_reg,
        w1, b1, ln_g, ln_b, w2, b2, ego_desc, other_desc);

    const int smem_bytes = (BQ*KPAD + BK*KPAD + BK*VSP) * sizeof(float); // 72,704 B
    hipFuncSetAttribute((const void*)attn_kernel,
                        hipFuncAttributeMaxDynamicSharedMemorySize, smem_bytes);
    attn_kernel<<<N_PIX/BQ, 256, smem_bytes, stream>>>(
        ego_desc, other_desc, other_cls, other_reg, (float*)d_out);
}

// Round 3
// 957.537 us; speedup vs baseline: 2.5351x; 2.5351x over previous
//
#include <hip/hip_runtime.h>
#include <math.h>

#define N_PIX 16384
#define EMB 128
#define LN_EPS 1e-5f
#define INV_TEMP 10.0f

#define BQ 64
#define BK 64
#define VSP 20
#define NT (N_PIX / BK)

typedef __attribute__((ext_vector_type(8))) short short8v;
typedef __attribute__((ext_vector_type(4))) float f32x4;

__device__ __forceinline__ void split_bf16(float x, unsigned short& h, unsigned short& l) {
    union { float f; unsigned u; } a; a.f = x;
    h = (unsigned short)(a.u >> 16);
    union { unsigned u; float f; } b; b.u = a.u & 0xFFFF0000u;
    float r = x - b.f;
    union { float f; unsigned u; } c; c.f = r;
    unsigned ru = c.u + 0x7FFFu + ((c.u >> 16) & 1u);   // RNE to bf16
    l = (unsigned short)(ru >> 16);
}

// ---------------------------------------------------------------------------
// Kernel 1: descriptor + MLP(6->128) + LN + MLP(128->128); emits bf16 hi/lo
// ---------------------------------------------------------------------------
__global__ __launch_bounds__(128) void encode_kernel(
    const float* __restrict__ ego_cls, const float* __restrict__ ego_reg,
    const float* __restrict__ other_cls, const float* __restrict__ other_reg,
    const float* __restrict__ w1, const float* __restrict__ b1,
    const float* __restrict__ ln_g, const float* __restrict__ ln_b,
    const float* __restrict__ w2, const float* __restrict__ b2,
    unsigned short* __restrict__ q_hi, unsigned short* __restrict__ q_lo,
    unsigned short* __restrict__ k_hi, unsigned short* __restrict__ k_lo)
{
    int r = blockIdx.x;
    const float* cls; const float* reg; unsigned short *ohi, *olo; int p;
    if (r < N_PIX) { cls = ego_cls;   reg = ego_reg;   ohi = q_hi; olo = q_lo; p = r; }
    else           { cls = other_cls; reg = other_reg; ohi = k_hi; olo = k_lo; p = r - N_PIX; }

    int j = threadIdx.x;

    float x0 = reg[3*N_PIX + p];
    float x1 = reg[4*N_PIX + p];
    float x2 = reg[5*N_PIX + p];
    float th = reg[6*N_PIX + p];
    float x3 = sinf(th);
    float x4 = cosf(th);
    float x5 = fmaxf(cls[p], cls[N_PIX + p]);

    float h = x0*w1[0*EMB+j] + x1*w1[1*EMB+j] + x2*w1[2*EMB+j]
            + x3*w1[3*EMB+j] + x4*w1[4*EMB+j] + x5*w1[5*EMB+j] + b1[j];
    h = fmaxf(h, 0.f);

    __shared__ float hn[EMB];
    __shared__ float red[4];

    float s = h, s2 = h*h;
    #pragma unroll
    for (int off = 32; off >= 1; off >>= 1) {
        s  += __shfl_xor(s,  off);
        s2 += __shfl_xor(s2, off);
    }
    int wid = j >> 6;
    if ((j & 63) == 0) { red[wid] = s; red[2+wid] = s2; }
    __syncthreads();
    float tot  = red[0] + red[1];
    float tot2 = red[2] + red[3];
    float mu  = tot * (1.f/EMB);
    float var = tot2 * (1.f/EMB) - mu*mu;
    float rstd = rsqrtf(var + LN_EPS);
    float hnj = (h - mu) * rstd * ln_g[j] + ln_b[j];
    hn[j] = hnj;
    __syncthreads();

    float acc = b2[j];
    #pragma unroll 8
    for (int k = 0; k < EMB; ++k)
        acc += hn[k] * w2[k*EMB + j];

    unsigned short hb, lb;
    split_bf16(acc, hb, lb);
    ohi[(size_t)p * EMB + j] = hb;
    olo[(size_t)p * EMB + j] = lb;
}

// ---------------------------------------------------------------------------
// Kernel 2: flash attention via MFMA bf16 (hi/lo x3 split precision)
// ---------------------------------------------------------------------------
__device__ __forceinline__ void gl_lds16(const void* g, void* l) {
    __builtin_amdgcn_global_load_lds(
        (const __attribute__((address_space(1))) unsigned int*)(g),
        (__attribute__((address_space(3))) unsigned int*)(l), 16, 0, 0);
}

__device__ __forceinline__ short8v mk8(short4 a, short4 b) {
    short8v r;
    r[0]=a.x; r[1]=a.y; r[2]=a.z; r[3]=a.w;
    r[4]=b.x; r[5]=b.y; r[6]=b.z; r[7]=b.w;
    return r;
}

// stage one K tile (hi+lo planes, 16KB each) into LDS at ldsbase
__device__ __forceinline__ void stage_K(
    const unsigned short* __restrict__ Kg_hi, const unsigned short* __restrict__ Kg_lo,
    char* ldsbase, int kb0, int w, int lane)
{
    #pragma unroll
    for (int pl = 0; pl < 2; ++pl) {
        const unsigned short* src = pl ? Kg_lo : Kg_hi;
        char* lb = ldsbase + pl * 16384;
        #pragma unroll
        for (int i = 0; i < 4; ++i) {
            int idx  = (w*4 + i)*64 + lane;        // 16B-chunk index in plane
            int row  = idx >> 4;                   // key row (0..63)
            int colb = (idx & 15) << 4;            // byte col in row (0..255)
            int scol = colb ^ ((row & 7) << 4);    // pre-swizzled source col
            const char* g = (const char*)src + ((size_t)(kb0 + row) << 8) + scol;
            gl_lds16(g, lb + (w*4 + i)*1024);      // HW adds lane*16
        }
    }
}

__global__ __launch_bounds__(256) void attn_kernel(
    const unsigned short* __restrict__ Qhi, const unsigned short* __restrict__ Qlo,
    const unsigned short* __restrict__ Khi, const unsigned short* __restrict__ Klo,
    const float* __restrict__ other_cls, const float* __restrict__ other_reg,
    float* __restrict__ out)
{
    extern __shared__ char smem[];
    // [buf][plane] K: 2*2*16KB = 64KB ; V: 2 * 64*VSP floats
    float* Vs0 = (float*)(smem + 65536);
    float* Vs1 = Vs0 + 64*VSP;

    const int tid  = threadIdx.x;
    const int w    = tid >> 6, lane = tid & 63;
    const int lg   = lane >> 4, lk = lane & 15;
    const int q0   = blockIdx.x * BQ;

    // ---- Q fragments in registers (reused for all 256 k-tiles) ----
    short8v qh[4], ql[4];
    {
        const int qrow = q0 + w*16 + lk;
        const unsigned short* qhp = Qhi + (size_t)qrow * EMB;
        const unsigned short* qlp = Qlo + (size_t)qrow * EMB;
        #pragma unroll
        for (int kk = 0; kk < 4; ++kk) {
            int base = kk*32 + lg*4;
            short4 a0 = *(const short4*)&qhp[base];
            short4 a1 = *(const short4*)&qhp[base + 16];
            qh[kk] = mk8(a0, a1);
            short4 b0 = *(const short4*)&qlp[base];
            short4 b1 = *(const short4*)&qlp[base + 16];
            ql[kk] = mk8(b0, b1);
        }
    }

    // ---- per-lane V load (4 floats) for a tile ----
    float vreg[4];
    int vc[4], vk[4];
    #pragma unroll
    for (int rr = 0; rr < 4; ++rr) {
        int idx = rr*256 + tid;
        vc[rr] = idx >> 6; vk[rr] = idx & 63;
    }

    // prologue: tile 0
    #pragma unroll
    for (int rr = 0; rr < 4; ++rr) {
        const float* vp = (vc[rr] < 2) ? (other_cls + vc[rr]*N_PIX)
                                       : (other_reg + (vc[rr]-2)*N_PIX);
        vreg[rr] = vp[vk[rr]];
    }
    stage_K(Khi, Klo, smem, 0, w, lane);
    #pragma unroll
    for (int rr = 0; rr < 4; ++rr) Vs0[vk[rr]*VSP + vc[rr]] = vreg[rr];
    __syncthreads();

    float mrow[4], lrow[4], accv[4][16];
    #pragma unroll
    for (int r = 0; r < 4; ++r) {
        mrow[r] = -INFINITY; lrow[r] = 0.f;
        #pragma unroll
        for (int c = 0; c < 16; ++c) accv[r][c] = 0.f;
    }

    // per-lane key columns + swizzle masks (constant over tiles)
    int keyy[4], kbase[4], kswz[4];
    #pragma unroll
    for (int n = 0; n < 4; ++n) {
        keyy[n]  = n*16 + lk;
        kbase[n] = keyy[n]*128 + lg*4;        // element units within plane
        kswz[n]  = (keyy[n] & 7) << 3;        // element-unit XOR (= byte XOR <<4)
    }

    for (int t = 0; t < NT; ++t) {
        const int cur = t & 1;
        const unsigned short* KhiL = (const unsigned short*)(smem + cur*32768);
        const unsigned short* KloL = KhiL + 8192;   // FIX: +8192 shorts = +16384 bytes
        const float* Vcur = cur ? Vs1 : Vs0;

        if (t + 1 < NT) {
            #pragma unroll
            for (int rr = 0; rr < 4; ++rr) {
                const float* vp = (vc[rr] < 2) ? (other_cls + vc[rr]*N_PIX)
                                               : (other_reg + (vc[rr]-2)*N_PIX);
                vreg[rr] = vp[(size_t)(t+1)*BK + vk[rr]];
            }
            stage_K(Khi, Klo, smem + (cur^1)*32768, (t+1)*BK, w, lane);
        }

        // ---- S = Q K^T via MFMA (hi*hi + hi*lo + lo*hi) ----
        f32x4 Sacc[4];
        #pragma unroll
        for (int n = 0; n < 4; ++n) { f32x4 z = {0.f,0.f,0.f,0.f}; Sacc[n] = z; }

        #pragma unroll
        for (int kk = 0; kk < 4; ++kk) {
            short8v bh[4], bl[4];
            #pragma unroll
            for (int n = 0; n < 4; ++n) {
                int e0 = (kbase[n] + kk*32)      ^ kswz[n];
                int e1 = (kbase[n] + kk*32 + 16) ^ kswz[n];
                bh[n] = mk8(*(const short4*)&KhiL[e0], *(const short4*)&KhiL[e1]);
                bl[n] = mk8(*(const short4*)&KloL[e0], *(const short4*)&KloL[e1]);
            }
            #pragma unroll
            for (int n = 0; n < 4; ++n)
                Sacc[n] = __builtin_amdgcn_mfma_f32_16x16x32_bf16(qh[kk], bh[n], Sacc[n], 0, 0, 0);
            #pragma unroll
            for (int n = 0; n < 4; ++n)
                Sacc[n] = __builtin_amdgcn_mfma_f32_16x16x32_bf16(qh[kk], bl[n], Sacc[n], 0, 0, 0);
            #pragma unroll
            for (int n = 0; n < 4; ++n)
                Sacc[n] = __builtin_amdgcn_mfma_f32_16x16x32_bf16(ql[kk], bh[n], Sacc[n], 0, 0, 0);
        }

        // ---- online softmax on C-frags: row=(lg*4+r), col(key)=16n+lk ----
        float P[4][4];
        #pragma unroll
        for (int r = 0; r < 4; ++r) {
            float mt = fmaxf(fmaxf(Sacc[0][r], Sacc[1][r]),
                             fmaxf(Sacc[2][r], Sacc[3][r])) * INV_TEMP;
            mt = fmaxf(mt, __shfl_xor(mt, 1));
            mt = fmaxf(mt, __shfl_xor(mt, 2));
            mt = fmaxf(mt, __shfl_xor(mt, 4));
            mt = fmaxf(mt, __shfl_xor(mt, 8));
            bool grow = mt > mrow[r];
            float mn = grow ? mt : mrow[r];
            float rsum = 0.f;
            #pragma unroll
            for (int n = 0; n < 4; ++n) {
                P[r][n] = __expf(Sacc[n][r] * INV_TEMP - mn);
                rsum += P[r][n];
            }
            rsum += __shfl_xor(rsum, 1);
            rsum += __shfl_xor(rsum, 2);
            rsum += __shfl_xor(rsum, 4);
            rsum += __shfl_xor(rsum, 8);
            if (grow) {
                float sc = __expf(mrow[r] - mt);
                mrow[r] = mt;
                lrow[r] = lrow[r]*sc + rsum;
                #pragma unroll
                for (int c = 0; c < 16; ++c) accv[r][c] *= sc;
            } else {
                lrow[r] += rsum;
            }
        }

        // ---- PV (VALU, 16 value cols) ----
        #pragma unroll
        for (int n = 0; n < 4; ++n) {
            const float* vr = &Vcur[keyy[n]*VSP];
            float4 v0 = *(const float4*)&vr[0];
            float4 v1 = *(const float4*)&vr[4];
            float4 v2 = *(const float4*)&vr[8];
            float4 v3 = *(const float4*)&vr[12];
            #pragma unroll
            for (int r = 0; r < 4; ++r) {
                float pp = P[r][n];
                accv[r][0]  += pp*v0.x; accv[r][1]  += pp*v0.y;
                accv[r][2]  += pp*v0.z; accv[r][3]  += pp*v0.w;
                accv[r][4]  += pp*v1.x; accv[r][5]  += pp*v1.y;
                accv[r][6]  += pp*v1.z; accv[r][7]  += pp*v1.w;
                accv[r][8]  += pp*v2.x; accv[r][9]  += pp*v2.y;
                accv[r][10] += pp*v2.z; accv[r][11] += pp*v2.w;
                accv[r][12] += pp*v3.x; accv[r][13] += pp*v3.y;
                accv[r][14] += pp*v3.z; accv[r][15] += pp*v3.w;
            }
        }

        if (t + 1 < NT) {
            float* Vnxt = (cur^1) ? Vs1 : Vs0;
            #pragma unroll
            for (int rr = 0; rr < 4; ++rr) Vnxt[vk[rr]*VSP + vc[rr]] = vreg[rr];
            __syncthreads();
        }
    }

    // ---- reduce over the 16 key-lanes, then write ----
    #pragma unroll
    for (int r = 0; r < 4; ++r) {
        #pragma unroll
        for (int c = 0; c < 16; ++c) {
            float v = accv[r][c];
            v += __shfl_xor(v, 1);
            v += __shfl_xor(v, 2);
            v += __shfl_xor(v, 4);
            v += __shfl_xor(v, 8);
            accv[r][c] = v;
        }
    }
    #pragma unroll
    for (int r = 0; r < 4; ++r) {
        float res = 0.f;
        #pragma unroll
        for (int c = 0; c < 16; ++c) if (lk == c) res = accv[r][c];
        int q = q0 + w*16 + lg*4 + r;
        out[(size_t)lk * N_PIX + q] = res / lrow[r];
    }
}

// ---------------------------------------------------------------------------
extern "C" void kernel_launch(void* const* d_in, const int* in_sizes, int n_in,
                              void* d_out, int out_size, void* d_ws, size_t ws_size,
                              hipStream_t stream) {
    const float* ego_cls   = (const float*)d_in[0];
    const float* ego_reg   = (const float*)d_in[1];
    const float* other_cls = (const float*)d_in[2];
    const float* other_reg = (const float*)d_in[3];
    const float* w1   = (const float*)d_in[4];
    const float* b1   = (const float*)d_in[5];
    const float* ln_g = (const float*)d_in[6];
    const float* ln_b = (const float*)d_in[7];
    const float* w2   = (const float*)d_in[8];
    const float* b2   = (const float*)d_in[9];

    unsigned short* qhi = (unsigned short*)d_ws;            // 4 MB each
    unsigned short* qlo = qhi + (size_t)N_PIX*EMB;
    unsigned short* khi = qlo + (size_t)N_PIX*EMB;
    unsigned short* klo = khi + (size_t)N_PIX*EMB;

    encode_kernel<<<2*N_PIX, 128, 0, stream>>>(
        ego_cls, ego_reg, other_cls, other_reg,
        w1, b1, ln_g, ln_b, w2, b2, qhi, qlo, khi, klo);

    const int smem_bytes = 65536 + 2*64*VSP*(int)sizeof(float);   // 75,776 B
    hipFuncSetAttribute((const void*)attn_kernel,
                        hipFuncAttributeMaxDynamicSharedMemorySize, smem_bytes);
    attn_kernel<<<N_PIX/BQ, 256, smem_bytes, stream>>>(
        qhi, qlo, khi, klo, other_cls, other_reg, (float*)d_out);
}

// Round 5
// 342.418 us; speedup vs baseline: 7.0892x; 2.7964x over previous
//
#include <hip/hip_runtime.h>
#include <math.h>

#define N_PIX 16384
#define EMB 128
#define LN_EPS 1e-5f
#define INV_TEMP 10.0f
#define BKT 32
#define NTILES (N_PIX / BKT)    // 512
#define SKIP_THR 25.0f

typedef __attribute__((ext_vector_type(8))) short short8v;
typedef __attribute__((ext_vector_type(4))) float f32x4;

__device__ __forceinline__ void split_bf16(float x, unsigned short& h, unsigned short& l) {
    union { float f; unsigned u; } a; a.f = x;
    h = (unsigned short)(a.u >> 16);
    union { unsigned u; float f; } b; b.u = a.u & 0xFFFF0000u;
    float r = x - b.f;
    union { float f; unsigned u; } c; c.f = r;
    unsigned ru = c.u + 0x7FFFu + ((c.u >> 16) & 1u);
    l = (unsigned short)(ru >> 16);
}

__device__ __forceinline__ short bf16rne(float x) {
    union { float f; unsigned u; } a; a.f = x;
    unsigned r = a.u + 0x7FFFu + ((a.u >> 16) & 1u);
    return (short)(r >> 16);
}

// ---------------------------------------------------------------------------
// Kernel 1: descriptor + MLP(6->128) + LN + MLP(128->128); emits bf16 hi/lo
// ---------------------------------------------------------------------------
__global__ __launch_bounds__(128) void encode_kernel(
    const float* __restrict__ ego_cls, const float* __restrict__ ego_reg,
    const float* __restrict__ other_cls, const float* __restrict__ other_reg,
    const float* __restrict__ w1, const float* __restrict__ b1,
    const float* __restrict__ ln_g, const float* __restrict__ ln_b,
    const float* __restrict__ w2, const float* __restrict__ b2,
    unsigned short* __restrict__ q_hi, unsigned short* __restrict__ q_lo,
    unsigned short* __restrict__ k_hi, unsigned short* __restrict__ k_lo)
{
    int r = blockIdx.x;
    const float* cls; const float* reg; unsigned short *ohi, *olo; int p;
    if (r < N_PIX) { cls = ego_cls;   reg = ego_reg;   ohi = q_hi; olo = q_lo; p = r; }
    else           { cls = other_cls; reg = other_reg; ohi = k_hi; olo = k_lo; p = r - N_PIX; }

    int j = threadIdx.x;

    float x0 = reg[3*N_PIX + p];
    float x1 = reg[4*N_PIX + p];
    float x2 = reg[5*N_PIX + p];
    float th = reg[6*N_PIX + p];
    float x3 = sinf(th);
    float x4 = cosf(th);
    float x5 = fmaxf(cls[p], cls[N_PIX + p]);

    float h = x0*w1[0*EMB+j] + x1*w1[1*EMB+j] + x2*w1[2*EMB+j]
            + x3*w1[3*EMB+j] + x4*w1[4*EMB+j] + x5*w1[5*EMB+j] + b1[j];
    h = fmaxf(h, 0.f);

    __shared__ float hn[EMB];
    __shared__ float red[4];

    float s = h, s2 = h*h;
    #pragma unroll
    for (int off = 32; off >= 1; off >>= 1) {
        s  += __shfl_xor(s,  off);
        s2 += __shfl_xor(s2, off);
    }
    int wid = j >> 6;
    if ((j & 63) == 0) { red[wid] = s; red[2+wid] = s2; }
    __syncthreads();
    float tot  = red[0] + red[1];
    float tot2 = red[2] + red[3];
    float mu  = tot * (1.f/EMB);
    float var = tot2 * (1.f/EMB) - mu*mu;
    float rstd = rsqrtf(var + LN_EPS);
    float hnj = (h - mu) * rstd * ln_g[j] + ln_b[j];
    hn[j] = hnj;
    __syncthreads();

    float acc = b2[j];
    #pragma unroll 8
    for (int k = 0; k < EMB; ++k)
        acc += hn[k] * w2[k*EMB + j];

    unsigned short hb, lb;
    split_bf16(acc, hb, lb);
    ohi[(size_t)p * EMB + j] = hb;
    olo[(size_t)p * EMB + j] = lb;
}

// ---------------------------------------------------------------------------
// Kernel 2: split-K flash attention, swapped-operand MFMA, tile skip.
// 2-buffer LDS double-buffering with TWO barriers/iter:
//   top: raw s_barrier after counted vmcnt(4)  (staged cur tile visible)
//   end: __syncthreads()  (all waves done reading cur before next stage overwrites)
// ---------------------------------------------------------------------------
__device__ __forceinline__ void gl_lds16(const void* g, void* l) {
    __builtin_amdgcn_global_load_lds(
        (const __attribute__((address_space(1))) unsigned int*)(g),
        (__attribute__((address_space(3))) unsigned int*)(l), 16, 0, 0);
}

__global__ __launch_bounds__(256, 4) void attn_kernel(
    const unsigned short* __restrict__ Qhi, const unsigned short* __restrict__ Qlo,
    const unsigned short* __restrict__ Khi, const unsigned short* __restrict__ Klo,
    const float* __restrict__ other_cls, const float* __restrict__ other_reg,
    float* __restrict__ macc, float* __restrict__ mbuf, float* __restrict__ lbuf,
    float* __restrict__ out, int S, int TPS, int XPS, int direct)
{
    __shared__ char Ks[2 * 16384];   // [buf][hi 8KB | lo 8KB]

    const int tid  = threadIdx.x;
    const int w    = tid >> 6, lane = tid & 63;
    const int lg   = lane >> 4, lk = lane & 15;

    // XCD-grouped bijective decode of blockIdx
    const int b  = blockIdx.x;
    const int s  = (b & 7) / XPS;
    const int qb = (b >> 3) * XPS + (b & 7) % XPS;
    const int qt0 = qb * 64 + w * 16;
    const int t0  = s * TPS;

    // ---- Q B-operand frags (k-map: k = kk*32 + lg*8 + e) ----
    short8v qbh[4], qbl[4];
    {
        const unsigned short* qh = Qhi + (size_t)(qt0 + lk) * EMB + lg*8;
        const unsigned short* ql = Qlo + (size_t)(qt0 + lk) * EMB + lg*8;
        #pragma unroll
        for (int kk = 0; kk < 4; ++kk) {
            qbh[kk] = *(const short8v*)(qh + kk*32);
            qbl[kk] = *(const short8v*)(ql + kk*32);
        }
    }

    // ---- staging precompute (4 gl_lds per wave per tile) ----
    int st_row[4], st_scol[4], st_pl[4], st_dst[4];
    #pragma unroll
    for (int i = 0; i < 4; ++i) {
        int ci = w*4 + i;
        int cb = (ci & 7) * 64 + lane;
        int row  = cb >> 4;
        int colb = (cb & 15) << 4;
        st_pl[i]  = ci >> 3;
        st_row[i] = row;
        st_scol[i] = colb ^ ((row & 7) << 4);
        st_dst[i] = (ci >> 3) * 8192 + (ci & 7) * 1024;   // + lane*16 (HW)
    }

    // ---- A-frag read offsets (bytes in plane) ----
    int koff[4];
    #pragma unroll
    for (int kk = 0; kk < 4; ++kk)
        koff[kk] = (kk*64 + lg*16) ^ ((lk & 7) << 4);

    const float* vplane = (lk < 2) ? (other_cls + lk * N_PIX)
                                   : (other_reg + (lk - 2) * N_PIX);

    float mrow = -INFINITY, lrow = 0.f;
    f32x4 accv = {0.f, 0.f, 0.f, 0.f};

    // prologue: stage tile t0 into buf 0
    {
        int kb0 = t0 * BKT;
        #pragma unroll
        for (int i = 0; i < 4; ++i) {
            const unsigned short* src = st_pl[i] ? Klo : Khi;
            const char* g = (const char*)src + (((size_t)(kb0 + st_row[i])) << 8) + st_scol[i];
            gl_lds16(g, Ks + st_dst[i]);
        }
    }

    int cur = 0;
    for (int tt = 0; tt < TPS; ++tt) {
        const int kb0 = (t0 + tt) * BKT;

        // V loads for CURRENT tile (issued before stage -> in-order vmcnt math exact)
        float vt[8];
        #pragma unroll
        for (int e = 0; e < 8; ++e)
            vt[e] = vplane[kb0 + 16*(e>>2) + lg*4 + (e&3)];

        if (tt + 1 < TPS) {
            int kn0 = (t0 + tt + 1) * BKT;
            char* dstb = Ks + (cur ^ 1) * 16384;
            #pragma unroll
            for (int i = 0; i < 4; ++i) {
                const unsigned short* src = st_pl[i] ? Klo : Khi;
                const char* g = (const char*)src + (((size_t)(kn0 + st_row[i])) << 8) + st_scol[i];
                gl_lds16(g, dstb + st_dst[i]);
            }
            asm volatile("s_waitcnt vmcnt(4)" ::: "memory");  // only next-tile stage outstanding
        } else {
            asm volatile("s_waitcnt vmcnt(0)" ::: "memory");
        }
        __builtin_amdgcn_sched_barrier(0);
        __builtin_amdgcn_s_barrier();
        __builtin_amdgcn_sched_barrier(0);

        const char* Bh = Ks + cur * 16384;
        const char* Bl = Bh + 8192;
        const int rowb = lk * 256;

        // ---- hi*hi pass: S[key][query] ----
        f32x4 S0 = {0,0,0,0}, S1 = {0,0,0,0};
        #pragma unroll
        for (int kk = 0; kk < 4; ++kk) {
            short8v a0 = *(const short8v*)(Bh + rowb + koff[kk]);
            short8v a1 = *(const short8v*)(Bh + 4096 + rowb + koff[kk]);
            S0 = __builtin_amdgcn_mfma_f32_16x16x32_bf16(a0, qbh[kk], S0, 0, 0, 0);
            S1 = __builtin_amdgcn_mfma_f32_16x16x32_bf16(a1, qbh[kk], S1, 0, 0, 0);
        }

        // ---- approx per-query tile max -> wave-uniform skip ----
        float mt = fmaxf(fmaxf(fmaxf(S0[0], S0[1]), fmaxf(S0[2], S0[3])),
                         fmaxf(fmaxf(S1[0], S1[1]), fmaxf(S1[2], S1[3])));
        mt = fmaxf(mt, __shfl_xor(mt, 16));
        mt = fmaxf(mt, __shfl_xor(mt, 32));
        if (__any(mt * INV_TEMP > mrow - SKIP_THR)) {
            // ---- cross terms: + kh*ql + kl*qh ----
            #pragma unroll
            for (int kk = 0; kk < 4; ++kk) {
                short8v ah0 = *(const short8v*)(Bh + rowb + koff[kk]);
                short8v ah1 = *(const short8v*)(Bh + 4096 + rowb + koff[kk]);
                short8v al0 = *(const short8v*)(Bl + rowb + koff[kk]);
                short8v al1 = *(const short8v*)(Bl + 4096 + rowb + koff[kk]);
                S0 = __builtin_amdgcn_mfma_f32_16x16x32_bf16(ah0, qbl[kk], S0, 0, 0, 0);
                S1 = __builtin_amdgcn_mfma_f32_16x16x32_bf16(ah1, qbl[kk], S1, 0, 0, 0);
                S0 = __builtin_amdgcn_mfma_f32_16x16x32_bf16(al0, qbh[kk], S0, 0, 0, 0);
                S1 = __builtin_amdgcn_mfma_f32_16x16x32_bf16(al1, qbh[kk], S1, 0, 0, 0);
            }

            // ---- exact online softmax (per-lane query = lk; x4 redundant) ----
            float m2 = fmaxf(fmaxf(fmaxf(S0[0], S0[1]), fmaxf(S0[2], S0[3])),
                             fmaxf(fmaxf(S1[0], S1[1]), fmaxf(S1[2], S1[3])));
            m2 = fmaxf(m2, __shfl_xor(m2, 16));
            m2 = fmaxf(m2, __shfl_xor(m2, 32));
            float mn = fmaxf(mrow, m2 * INV_TEMP);
            float p[8]; float rs = 0.f;
            #pragma unroll
            for (int r = 0; r < 4; ++r) { p[r]   = __expf(S0[r]*INV_TEMP - mn); rs += p[r];   }
            #pragma unroll
            for (int r = 0; r < 4; ++r) { p[4+r] = __expf(S1[r]*INV_TEMP - mn); rs += p[4+r]; }
            rs += __shfl_xor(rs, 16);
            rs += __shfl_xor(rs, 32);
            float sc = __expf(mrow - mn);
            lrow = lrow * sc + rs;
            mrow = mn;

            // ---- rescale O accumulator (4 values) ----
            #pragma unroll
            for (int r = 0; r < 4; ++r)
                accv[r] *= __shfl(sc, lg*4 + r);

            // ---- PV: one MFMA. A=P[query][key32], B=V[key32][col16],
            //      both using key-map pi(l,e)=16*(e>>2)+lg*4+(e&3) ----
            short8v pa, vb;
            #pragma unroll
            for (int e = 0; e < 8; ++e) vb[e] = bf16rne(vt[e]);
            #pragma unroll
            for (int r = 0; r < 4; ++r) { pa[r] = bf16rne(p[r]); pa[4+r] = bf16rne(p[4+r]); }
            accv = __builtin_amdgcn_mfma_f32_16x16x32_bf16(pa, vb, accv, 0, 0, 0);
        }

        __syncthreads();   // WAR fence: all waves done reading buf `cur`
        cur ^= 1;
    }

    // ---- write ----
    if (direct) {
        #pragma unroll
        for (int r = 0; r < 4; ++r) {
            float lqr = __shfl(lrow, lg*4 + r);
            out[(size_t)lk * N_PIX + qt0 + lg*4 + r] = accv[r] / lqr;
        }
    } else {
        #pragma unroll
        for (int r = 0; r < 4; ++r)
            macc[((size_t)(s*16 + lk)) * N_PIX + qt0 + lg*4 + r] = accv[r];
        if (lane < 16) {
            mbuf[(size_t)s * N_PIX + qt0 + lane] = mrow;
            lbuf[(size_t)s * N_PIX + qt0 + lane] = lrow;
        }
    }
}

// ---------------------------------------------------------------------------
// Kernel 3: merge split-K partials.
// ---------------------------------------------------------------------------
__global__ __launch_bounds__(256) void merge_kernel(
    const float* __restrict__ macc, const float* __restrict__ mbuf,
    const float* __restrict__ lbuf, float* __restrict__ out, int S)
{
    int tid = blockIdx.x * 256 + threadIdx.x;   // 0 .. 16*N_PIX-1
    int q = tid & (N_PIX - 1);
    int c = tid >> 14;
    float M = -INFINITY;
    for (int s = 0; s < S; ++s) M = fmaxf(M, mbuf[s*N_PIX + q]);
    float L = 0.f, O = 0.f;
    for (int s = 0; s < S; ++s) {
        float e = __expf(mbuf[s*N_PIX + q] - M);
        L += lbuf[s*N_PIX + q] * e;
        O += macc[((size_t)(s*16 + c)) * N_PIX + q] * e;
    }
    out[tid] = O / L;
}

// ---------------------------------------------------------------------------
extern "C" void kernel_launch(void* const* d_in, const int* in_sizes, int n_in,
                              void* d_out, int out_size, void* d_ws, size_t ws_size,
                              hipStream_t stream) {
    const float* ego_cls   = (const float*)d_in[0];
    const float* ego_reg   = (const float*)d_in[1];
    const float* other_cls = (const float*)d_in[2];
    const float* other_reg = (const float*)d_in[3];
    const float* w1   = (const float*)d_in[4];
    const float* b1   = (const float*)d_in[5];
    const float* ln_g = (const float*)d_in[6];
    const float* ln_b = (const float*)d_in[7];
    const float* w2   = (const float*)d_in[8];
    const float* b2   = (const float*)d_in[9];

    unsigned short* qhi = (unsigned short*)d_ws;            // 4 MB each
    unsigned short* qlo = qhi + (size_t)N_PIX*EMB;
    unsigned short* khi = qlo + (size_t)N_PIX*EMB;
    unsigned short* klo = khi + (size_t)N_PIX*EMB;
    const size_t planes_bytes = (size_t)4 * N_PIX * EMB * 2;  // 16 MB

    auto need = [&](int S) { return planes_bytes + (size_t)S * N_PIX * 4 * 18; };
    int S = 1, direct = 1;
    if (ws_size >= need(4))      { S = 4; direct = 0; }
    else if (ws_size >= need(2)) { S = 2; direct = 0; }
    int TPS = NTILES / S;
    int XPS = 8 / S;

    float* macc = (float*)((char*)d_ws + planes_bytes);     // [S][16][N]
    float* mbuf = macc + (size_t)S * 16 * N_PIX;            // [S][N]
    float* lbuf = mbuf + (size_t)S * N_PIX;                 // [S][N]

    encode_kernel<<<2*N_PIX, 128, 0, stream>>>(
        ego_cls, ego_reg, other_cls, other_reg,
        w1, b1, ln_g, ln_b, w2, b2, qhi, qlo, khi, klo);

    attn_kernel<<<256*S, 256, 0, stream>>>(
        qhi, qlo, khi, klo, other_cls, other_reg,
        macc, mbuf, lbuf, (float*)d_out, S, TPS, XPS, direct);

    if (!direct)
        merge_kernel<<<(16*N_PIX)/256, 256, 0, stream>>>(
            macc, mbuf, lbuf, (float*)d_out, S);
}

// Round 6
// 334.447 us; speedup vs baseline: 7.2582x; 1.0238x over previous
//
#include <hip/hip_runtime.h>
#include <math.h>

#define N_PIX 16384
#define EMB 128
#define LN_EPS 1e-5f
#define INV_TEMP 10.0f
#define C2 14.4269504f          // INV_TEMP * log2(e): logits in log2 units
#define THR2 26.0f              // skip threshold (log2 units) ~= 18 nats
#define BKT 32
#define NTILES (N_PIX / BKT)    // 512

typedef __attribute__((ext_vector_type(8))) short short8v;
typedef __attribute__((ext_vector_type(4))) float f32x4;

__device__ __forceinline__ float fexp2(float x) {
#if __has_builtin(__builtin_amdgcn_exp2f)
    return __builtin_amdgcn_exp2f(x);
#else
    float r; asm("v_exp_f32 %0, %1" : "=v"(r) : "v"(x)); return r;
#endif
}

__device__ __forceinline__ unsigned cvt_pk_bf16(float lo, float hi) {
    unsigned r;
    asm("v_cvt_pk_bf16_f32 %0, %1, %2" : "=v"(r) : "v"(lo), "v"(hi));
    return r;
}

__device__ __forceinline__ void split_bf16(float x, unsigned short& h, unsigned short& l) {
    union { float f; unsigned u; } a; a.f = x;
    h = (unsigned short)(a.u >> 16);
    union { unsigned u; float f; } b; b.u = a.u & 0xFFFF0000u;
    float r = x - b.f;
    union { float f; unsigned u; } c; c.f = r;
    unsigned ru = c.u + 0x7FFFu + ((c.u >> 16) & 1u);
    l = (unsigned short)(ru >> 16);
}

// ---------------------------------------------------------------------------
// Kernel 1: descriptor + MLP(6->128) + LN + MLP(128->128); emits bf16 hi/lo
// ---------------------------------------------------------------------------
__global__ __launch_bounds__(128) void encode_kernel(
    const float* __restrict__ ego_cls, const float* __restrict__ ego_reg,
    const float* __restrict__ other_cls, const float* __restrict__ other_reg,
    const float* __restrict__ w1, const float* __restrict__ b1,
    const float* __restrict__ ln_g, const float* __restrict__ ln_b,
    const float* __restrict__ w2, const float* __restrict__ b2,
    unsigned short* __restrict__ q_hi, unsigned short* __restrict__ q_lo,
    unsigned short* __restrict__ k_hi, unsigned short* __restrict__ k_lo)
{
    int r = blockIdx.x;
    const float* cls; const float* reg; unsigned short *ohi, *olo; int p;
    if (r < N_PIX) { cls = ego_cls;   reg = ego_reg;   ohi = q_hi; olo = q_lo; p = r; }
    else           { cls = other_cls; reg = other_reg; ohi = k_hi; olo = k_lo; p = r - N_PIX; }

    int j = threadIdx.x;

    float x0 = reg[3*N_PIX + p];
    float x1 = reg[4*N_PIX + p];
    float x2 = reg[5*N_PIX + p];
    float th = reg[6*N_PIX + p];
    float x3 = sinf(th);
    float x4 = cosf(th);
    float x5 = fmaxf(cls[p], cls[N_PIX + p]);

    float h = x0*w1[0*EMB+j] + x1*w1[1*EMB+j] + x2*w1[2*EMB+j]
            + x3*w1[3*EMB+j] + x4*w1[4*EMB+j] + x5*w1[5*EMB+j] + b1[j];
    h = fmaxf(h, 0.f);

    __shared__ float hn[EMB];
    __shared__ float red[4];

    float s = h, s2 = h*h;
    #pragma unroll
    for (int off = 32; off >= 1; off >>= 1) {
        s  += __shfl_xor(s,  off);
        s2 += __shfl_xor(s2, off);
    }
    int wid = j >> 6;
    if ((j & 63) == 0) { red[wid] = s; red[2+wid] = s2; }
    __syncthreads();
    float tot  = red[0] + red[1];
    float tot2 = red[2] + red[3];
    float mu  = tot * (1.f/EMB);
    float var = tot2 * (1.f/EMB) - mu*mu;
    float rstd = rsqrtf(var + LN_EPS);
    float hnj = (h - mu) * rstd * ln_g[j] + ln_b[j];
    hn[j] = hnj;
    __syncthreads();

    float acc = b2[j];
    #pragma unroll 8
    for (int k = 0; k < EMB; ++k)
        acc += hn[k] * w2[k*EMB + j];

    unsigned short hb, lb;
    split_bf16(acc, hb, lb);
    ohi[(size_t)p * EMB + j] = hb;
    olo[(size_t)p * EMB + j] = lb;
}

// ---------------------------------------------------------------------------
// Kernel 2: split-K flash attention, swapped-operand MFMA, tile skip.
//   top: counted vmcnt + raw s_barrier ; bottom: __syncthreads (WAR fence)
//   softmax in log2 domain; pa/vb packed via v_cvt_pk_bf16_f32.
// ---------------------------------------------------------------------------
__device__ __forceinline__ void gl_lds16(const void* g, void* l) {
    __builtin_amdgcn_global_load_lds(
        (const __attribute__((address_space(1))) unsigned int*)(g),
        (__attribute__((address_space(3))) unsigned int*)(l), 16, 0, 0);
}

__global__ __launch_bounds__(256, 8) void attn_kernel(
    const unsigned short* __restrict__ Qhi, const unsigned short* __restrict__ Qlo,
    const unsigned short* __restrict__ Khi, const unsigned short* __restrict__ Klo,
    const float* __restrict__ other_cls, const float* __restrict__ other_reg,
    float* __restrict__ macc, float* __restrict__ mbuf, float* __restrict__ lbuf,
    float* __restrict__ out, int S, int TPS, int XPS, int direct)
{
    __shared__ char Ks[2 * 16384];   // [buf][hi 8KB | lo 8KB]

    const int tid  = threadIdx.x;
    const int w    = tid >> 6, lane = tid & 63;
    const int lg   = lane >> 4, lk = lane & 15;

    // XCD-grouped bijective decode: slice pinned per XCD (K-slice L2-resident)
    const int b  = blockIdx.x;
    const int s  = (b & 7) / XPS;
    const int qb = (b >> 3) * XPS + (b & 7) % XPS;
    const int qt0 = qb * 64 + w * 16;
    const int t0  = s * TPS;

    // ---- Q B-operand frags (k-map: k = kk*32 + lg*8 + e) ----
    short8v qbh[4], qbl[4];
    {
        const unsigned short* qh = Qhi + (size_t)(qt0 + lk) * EMB + lg*8;
        const unsigned short* ql = Qlo + (size_t)(qt0 + lk) * EMB + lg*8;
        #pragma unroll
        for (int kk = 0; kk < 4; ++kk) {
            qbh[kk] = *(const short8v*)(qh + kk*32);
            qbl[kk] = *(const short8v*)(ql + kk*32);
        }
    }

    // ---- staging precompute (4 gl_lds per wave per tile) ----
    int st_row[4], st_scol[4], st_pl[4], st_dst[4];
    #pragma unroll
    for (int i = 0; i < 4; ++i) {
        int ci = w*4 + i;
        int cb = (ci & 7) * 64 + lane;
        int row  = cb >> 4;
        int colb = (cb & 15) << 4;
        st_pl[i]  = ci >> 3;
        st_row[i] = row;
        st_scol[i] = colb ^ ((row & 7) << 4);
        st_dst[i] = (ci >> 3) * 8192 + (ci & 7) * 1024;   // + lane*16 (HW)
    }

    // ---- A-frag read offsets (bytes in plane) ----
    int koff[4];
    #pragma unroll
    for (int kk = 0; kk < 4; ++kk)
        koff[kk] = (kk*64 + lg*16) ^ ((lk & 7) << 4);

    const float* vplane = (lk < 2) ? (other_cls + lk * N_PIX)
                                   : (other_reg + (lk - 2) * N_PIX);

    float mrow = -INFINITY, lrow = 0.f;   // mrow in log2 units
    f32x4 accv = {0.f, 0.f, 0.f, 0.f};

    // prologue: stage tile t0 into buf 0
    {
        int kb0 = t0 * BKT;
        #pragma unroll
        for (int i = 0; i < 4; ++i) {
            const unsigned short* src = st_pl[i] ? Klo : Khi;
            const char* g = (const char*)src + (((size_t)(kb0 + st_row[i])) << 8) + st_scol[i];
            gl_lds16(g, Ks + st_dst[i]);
        }
    }

    int cur = 0;
    for (int tt = 0; tt < TPS; ++tt) {
        const int kb0 = (t0 + tt) * BKT;

        if (tt + 1 < TPS) {
            int kn0 = (t0 + tt + 1) * BKT;
            char* dstb = Ks + (cur ^ 1) * 16384;
            #pragma unroll
            for (int i = 0; i < 4; ++i) {
                const unsigned short* src = st_pl[i] ? Klo : Khi;
                const char* g = (const char*)src + (((size_t)(kn0 + st_row[i])) << 8) + st_scol[i];
                gl_lds16(g, dstb + st_dst[i]);
            }
            asm volatile("s_waitcnt vmcnt(4)" ::: "memory");  // only next-tile stage outstanding
        } else {
            asm volatile("s_waitcnt vmcnt(0)" ::: "memory");
        }
        __builtin_amdgcn_sched_barrier(0);
        __builtin_amdgcn_s_barrier();
        __builtin_amdgcn_sched_barrier(0);

        const char* Bh = Ks + cur * 16384;
        const char* Bl = Bh + 8192;
        const int rowb = lk * 256;

        // ---- hi*hi pass: S[key][query] ----
        f32x4 S0 = {0,0,0,0}, S1 = {0,0,0,0};
        #pragma unroll
        for (int kk = 0; kk < 4; ++kk) {
            short8v a0 = *(const short8v*)(Bh + rowb + koff[kk]);
            short8v a1 = *(const short8v*)(Bh + 4096 + rowb + koff[kk]);
            S0 = __builtin_amdgcn_mfma_f32_16x16x32_bf16(a0, qbh[kk], S0, 0, 0, 0);
            S1 = __builtin_amdgcn_mfma_f32_16x16x32_bf16(a1, qbh[kk], S1, 0, 0, 0);
        }

        // ---- approx per-query tile max -> wave-uniform skip ----
        float mt = fmaxf(fmaxf(fmaxf(S0[0], S0[1]), fmaxf(S0[2], S0[3])),
                         fmaxf(fmaxf(S1[0], S1[1]), fmaxf(S1[2], S1[3])));
        mt = fmaxf(mt, __shfl_xor(mt, 16));
        mt = fmaxf(mt, __shfl_xor(mt, 32));
        if (__any(mt * C2 > mrow - THR2)) {
            // V loads for this tile (taken tiles only; drained by use below)
            float vt[8];
            #pragma unroll
            for (int e = 0; e < 8; ++e)
                vt[e] = vplane[kb0 + 16*(e>>2) + lg*4 + (e&3)];

            // ---- cross terms: + kh*ql + kl*qh ----
            #pragma unroll
            for (int kk = 0; kk < 4; ++kk) {
                short8v ah0 = *(const short8v*)(Bh + rowb + koff[kk]);
                short8v ah1 = *(const short8v*)(Bh + 4096 + rowb + koff[kk]);
                short8v al0 = *(const short8v*)(Bl + rowb + koff[kk]);
                short8v al1 = *(const short8v*)(Bl + 4096 + rowb + koff[kk]);
                S0 = __builtin_amdgcn_mfma_f32_16x16x32_bf16(ah0, qbl[kk], S0, 0, 0, 0);
                S1 = __builtin_amdgcn_mfma_f32_16x16x32_bf16(ah1, qbl[kk], S1, 0, 0, 0);
                S0 = __builtin_amdgcn_mfma_f32_16x16x32_bf16(al0, qbh[kk], S0, 0, 0, 0);
                S1 = __builtin_amdgcn_mfma_f32_16x16x32_bf16(al1, qbh[kk], S1, 0, 0, 0);
            }

            // ---- exact online softmax in log2 domain ----
            float rm = fmaxf(fmaxf(fmaxf(S0[0], S0[1]), fmaxf(S0[2], S0[3])),
                             fmaxf(fmaxf(S1[0], S1[1]), fmaxf(S1[2], S1[3])));
            rm = fmaxf(rm, __shfl_xor(rm, 16));
            rm = fmaxf(rm, __shfl_xor(rm, 32));
            float mn = fmaxf(mrow, rm * C2);
            float p[8]; float rs = 0.f;
            #pragma unroll
            for (int r = 0; r < 4; ++r) { p[r]   = fexp2(fmaf(S0[r], C2, -mn)); rs += p[r];   }
            #pragma unroll
            for (int r = 0; r < 4; ++r) { p[4+r] = fexp2(fmaf(S1[r], C2, -mn)); rs += p[4+r]; }
            rs += __shfl_xor(rs, 16);
            rs += __shfl_xor(rs, 32);
            float sc = fexp2(mrow - mn);
            lrow = lrow * sc + rs;
            mrow = mn;

            // ---- rescale O accumulator (4 values) ----
            #pragma unroll
            for (int r = 0; r < 4; ++r)
                accv[r] *= __shfl(sc, lg*4 + r);

            // ---- PV: one MFMA. key-map pi(l,e)=16*(e>>2)+lg*4+(e&3) on both ----
            union { short8v v; unsigned u[4]; } pa, vb;
            #pragma unroll
            for (int d = 0; d < 4; ++d) {
                pa.u[d] = cvt_pk_bf16(p[2*d],  p[2*d+1]);
                vb.u[d] = cvt_pk_bf16(vt[2*d], vt[2*d+1]);
            }
            accv = __builtin_amdgcn_mfma_f32_16x16x32_bf16(pa.v, vb.v, accv, 0, 0, 0);
        }

        __syncthreads();   // WAR fence: all waves done reading buf `cur`
        cur ^= 1;
    }

    // ---- write ----
    if (direct) {
        #pragma unroll
        for (int r = 0; r < 4; ++r) {
            float lqr = __shfl(lrow, lg*4 + r);
            out[(size_t)lk * N_PIX + qt0 + lg*4 + r] = accv[r] / lqr;
        }
    } else {
        #pragma unroll
        for (int r = 0; r < 4; ++r)
            macc[((size_t)(s*16 + lk)) * N_PIX + qt0 + lg*4 + r] = accv[r];
        if (lane < 16) {
            mbuf[(size_t)s * N_PIX + qt0 + lane] = mrow;
            lbuf[(size_t)s * N_PIX + qt0 + lane] = lrow;
        }
    }
}

// ---------------------------------------------------------------------------
// Kernel 3: merge split-K partials (m in log2 units).
// ---------------------------------------------------------------------------
__global__ __launch_bounds__(256) void merge_kernel(
    const float* __restrict__ macc, const float* __restrict__ mbuf,
    const float* __restrict__ lbuf, float* __restrict__ out, int S)
{
    int tid = blockIdx.x * 256 + threadIdx.x;   // 0 .. 16*N_PIX-1
    int q = tid & (N_PIX - 1);
    int c = tid >> 14;
    float M = -INFINITY;
    for (int s = 0; s < S; ++s) M = fmaxf(M, mbuf[s*N_PIX + q]);
    float L = 0.f, O = 0.f;
    for (int s = 0; s < S; ++s) {
        float e = fexp2(mbuf[s*N_PIX + q] - M);
        L += lbuf[s*N_PIX + q] * e;
        O += macc[((size_t)(s*16 + c)) * N_PIX + q] * e;
    }
    out[tid] = O / L;
}

// ---------------------------------------------------------------------------
extern "C" void kernel_launch(void* const* d_in, const int* in_sizes, int n_in,
                              void* d_out, int out_size, void* d_ws, size_t ws_size,
                              hipStream_t stream) {
    const float* ego_cls   = (const float*)d_in[0];
    const float* ego_reg   = (const float*)d_in[1];
    const float* other_cls = (const float*)d_in[2];
    const float* other_reg = (const float*)d_in[3];
    const float* w1   = (const float*)d_in[4];
    const float* b1   = (const float*)d_in[5];
    const float* ln_g = (const float*)d_in[6];
    const float* ln_b = (const float*)d_in[7];
    const float* w2   = (const float*)d_in[8];
    const float* b2   = (const float*)d_in[9];

    unsigned short* qhi = (unsigned short*)d_ws;            // 4 MB each
    unsigned short* qlo = qhi + (size_t)N_PIX*EMB;
    unsigned short* khi = qlo + (size_t)N_PIX*EMB;
    unsigned short* klo = khi + (size_t)N_PIX*EMB;
    const size_t planes_bytes = (size_t)4 * N_PIX * EMB * 2;  // 16 MB

    auto need = [&](int S) { return planes_bytes + (size_t)S * N_PIX * 4 * 18; };
    int S = 1, direct = 1;
    if      (ws_size >= need(8)) { S = 8; direct = 0; }
    else if (ws_size >= need(4)) { S = 4; direct = 0; }
    else if (ws_size >= need(2)) { S = 2; direct = 0; }
    int TPS = NTILES / S;
    int XPS = 8 / S;

    float* macc = (float*)((char*)d_ws + planes_bytes);     // [S][16][N]
    float* mbuf = macc + (size_t)S * 16 * N_PIX;            // [S][N]
    float* lbuf = mbuf + (size_t)S * N_PIX;                 // [S][N]

    encode_kernel<<<2*N_PIX, 128, 0, stream>>>(
        ego_cls, ego_reg, other_cls, other_reg,
        w1, b1, ln_g, ln_b, w2, b2, qhi, qlo, khi, klo);

    attn_kernel<<<256*S, 256, 0, stream>>>(
        qhi, qlo, khi, klo, other_cls, other_reg,
        macc, mbuf, lbuf, (float*)d_out, S, TPS, XPS, direct);

    if (!direct)
        merge_kernel<<<(16*N_PIX)/256, 256, 0, stream>>>(
            macc, mbuf, lbuf, (float*)d_out, S);
}